// Round 12
// baseline (1979.931 us; speedup 1.0000x reference)
//
#include <hip/hip_runtime.h>
#include <hip/hip_bf16.h>
#include <math.h>

#define VB 50000
#define EE 256
#define UU 512
#define BB 256
#define TT 256
#define G4 2048

typedef __attribute__((ext_vector_type(8))) short short8;
typedef __attribute__((ext_vector_type(2))) unsigned long long u64x2;
typedef __attribute__((ext_vector_type(4))) float f32x4;

__device__ __forceinline__ float sigf(float x){ return 1.0f/(1.0f+expf(-x)); }
__device__ __forceinline__ unsigned short f2bf(float f){
    __hip_bfloat16 h = __float2bfloat16(f);   // RNE
    unsigned short s; __builtin_memcpy(&s,&h,2); return s;
}
__device__ __forceinline__ float bf2f(unsigned short u){
    unsigned int x = ((unsigned int)u)<<16; float f; __builtin_memcpy(&f,&x,4); return f;
}

// agent-scope flag ops (4B) -- polls must stay uncached
__device__ __forceinline__ unsigned int cldu(const unsigned int* p){
    return __hip_atomic_load(p, __ATOMIC_RELAXED, __HIP_MEMORY_SCOPE_AGENT);
}
__device__ __forceinline__ void cstu(unsigned int* p, unsigned int v){
    __hip_atomic_store(p, v, __ATOMIC_RELAXED, __HIP_MEMORY_SCOPE_AGENT);
}

// 16B PLAIN CACHED load (L1+per-XCD L2): one transaction, L2-shareable across
// the ~8 blocks of an XCD. NO waitcnt inside -- caller does s_waitcnt vmcnt(N)
// + sched_barrier(0) before first use (rule #18).
__device__ __forceinline__ short8 cld16c(const unsigned short* p){
    short8 v;
    asm volatile("global_load_dwordx4 %0, %1, off"
                 : "=&v"(v) : "v"(p));
    return v;
}
// 16B agent-scope coherent STORE (sc1): writer side must reach the coherent
// point before the flag -- unchanged from R10/R11.
__device__ __forceinline__ void cst16w(unsigned long long* dp, u64x2 v){
    asm volatile("global_store_dwordx4 %0, %1, off sc1"
                 :: "v"(dp), "v"(v) : "memory");
}

// ---------- pre-pass: transpose+convert W [rows][2048] fp32 -> out[c][koff+k] bf16 ----------
__global__ __launch_bounds__(256) void wtrans(const float* __restrict__ in, int rows,
                                              unsigned short* __restrict__ out,
                                              int Kout, int koff) {
    __shared__ float tl[32][33];
    int tx = threadIdx.x, ty = threadIdx.y;
    int c0 = blockIdx.x * 32, k0 = blockIdx.y * 32;
    #pragma unroll
    for (int i = 0; i < 4; i++)
        tl[ty + i * 8][tx] = in[(size_t)(k0 + ty + i * 8) * G4 + c0 + tx];
    __syncthreads();
    #pragma unroll
    for (int i = 0; i < 4; i++)
        out[(size_t)(c0 + ty + i * 8) * Kout + koff + k0 + tx] = f2bf(tl[tx][ty + i * 8]);
}

// ---------- pre-pass: gather embeddings -> xbf[t][b][k] bf16 ----------
__global__ __launch_bounds__(64) void xgather(const int* __restrict__ tokens,
                                              const float* __restrict__ emb,
                                              unsigned short* __restrict__ xbf) {
    int flat = blockIdx.x;
    int b = flat & 255, t = flat >> 8;
    int tok = tokens[b * TT + t];
    float4 v = ((const float4*)(emb + (size_t)tok * EE))[threadIdx.x];
    ushort4 o;
    o.x = f2bf(v.x); o.y = f2bf(v.y); o.z = f2bf(v.z); o.w = f2bf(v.w);
    ((ushort4*)(xbf + ((size_t)t * BB + b) * EE))[threadIdx.x] = o;
}

// ---------- persistent 2-layer LSTM: L2-SHARED h reads ----------
// BASE = R11 (1922us): two-phase L1 wait, counted vmcnt, 16B coherent traffic,
// lane-ordered LDS weights, hst staging, 4B-stride flags.
// This round: h READS become PLAIN CACHED loads (per-XCD L2 shared: coherent
// read transactions drop ~8x from the 32x u-slice broadcast redundancy),
// enabled by:
//  * 16-deep rings (slot = p&15): address reuse distance = 16 steps.
//  * per-block agent-ACQUIRE fence every 8 own-steps (invalidates own XCD
//    L1+L2): any stale line (age >= 8 steps in own-step time) is purged
//    before reuse. Stale copies younger than one fence period cannot exist
//    for a to-be-read address because all readers of address A=slot s read
//    h(p0) within maxSkew (<8) steps of each other, and the next use of A is
//    h(p0+16). Skew bounds: L0<->L0, L1<->L1 <=~1 (per-step flags); L0->L1
//    capped at 6 by L0's deferred overwrite gate; L1 never leads L0.
//  * writes stay sc1 (visible at coherent point before flag; consumer's L2
//    miss fetches them). R6 measured this exact produce-sc1/fence/plain-read
//    chain returning absmax 0.0.
// L0's L1-flag gate (slack 6) moves to POST-compute (pre-store): off the
// pre-load critical path.  Arithmetic byte-identical to R11.
__global__ __launch_bounds__(256, 1) void rnn_persist(
    const unsigned short* __restrict__ Wt0,   // [2048][768]  bf16 [col][k]
    const unsigned short* __restrict__ Wt1,   // [2048][1024]
    const unsigned short* __restrict__ xbf,   // [256][256][256] bf16 (or unused)
    const int* __restrict__ tokens, const float* __restrict__ emb,
    const float* __restrict__ b0v, const float* __restrict__ b1v,
    unsigned short* __restrict__ h0buf,       // [16][256][512] bf16 ring
    unsigned short* __restrict__ h1buf,       // [16][256][512] bf16 ring
    unsigned int* __restrict__ bars,          // per group 1024 uints (4KB)
    int use_xbf)
{
    extern __shared__ char smem[];
    unsigned short* wl  = (unsigned short*)smem;               // lane-ordered weights (<=128KB)
    unsigned short* hst = (unsigned short*)(smem + 131072);    // 64x16 h staging, stride 24 (3KB)
    int*            tokl = (int*)(smem + 131072 + 3072);       // 64 ints

    const int tid   = threadIdx.x;
    const int bid   = blockIdx.x;
    const int g     = bid >> 6;
    const int local = bid & 63;
    const int layer = local >> 5;
    const int u0    = (local & 31) * 16;
    const int row0  = g * 64;
    const int K     = layer ? 1024 : 768;
    const int KT    = K / 32;                  // 24 or 32 k-tiles
    const unsigned short* Wt = layer ? Wt1 : Wt0;
    const float* bR = layer ? b1v : b0v;

    // ---- fill LDS weights, LANE-ordered chunks: i = ((gate*KT+kt)*64 + (q*16+n)) ----
    const int nch = 4 * KT * 64;
    for (int i = tid; i < nch; i += 256) {
        int n  = i & 15;
        int q2 = (i >> 4) & 3;
        int t2 = i >> 6;
        int kt = t2 % KT, gate = t2 / KT;
        const unsigned short* src = Wt + (size_t)(gate * UU + u0 + n) * K + kt * 32 + q2 * 8;
        *(short8*)(wl + (size_t)i * 8) = *(const short8*)src;
    }

    float gb[4];
    #pragma unroll
    for (int gate = 0; gate < 4; gate++) gb[gate] = bR[gate * UU + u0 + (tid & 15)];
    float cst[4] = {0.f, 0.f, 0.f, 0.f};

    const int lane = tid & 63;
    const int w    = tid >> 6;
    const int n16  = lane & 15;
    const int q    = lane >> 4;
    const int q8   = q * 8;
    const int myrow = row0 + w * 16 + n16;
    const unsigned short* wlane = wl + lane * 8;   // + (gate*KT+kt)*512 shorts

    // flag region for this group: flag(local) at 4B stride
    unsigned int* flg = bars + (size_t)g * 1024;
    unsigned int* myFlag = flg + local;
    const unsigned int* pollp = flg + lane;        // lane L polls flag of block L

    const size_t HS = (size_t)BB * UU;

    __syncthreads();   // wl ready

    for (int p = 0; p <= TT; p++) {
        // ---- periodic L1+L2 invalidate: purges any stale ring lines (and
        // inter-launch leftovers at p=0) before this step's reads ----
        if ((p & 7) == 0)
            __builtin_amdgcn_fence(__ATOMIC_ACQUIRE, "agent");

        f32x4 acc[4];
        #pragma unroll
        for (int gate = 0; gate < 4; gate++)
            acc[gate] = (f32x4){gb[gate], gb[gate], gb[gate], gb[gate]};

        // ---- L0 x-part (static inputs) BEFORE the wait ----
        short8 xv[8];
        if (layer == 0 && p < TT) {
            if (!use_xbf) {
                if (tid < 64) tokl[tid] = tokens[(size_t)(row0 + tid) * TT + p];
                __syncthreads();
                const float* ep = emb + (size_t)tokl[w * 16 + n16] * EE + q8;
                #pragma unroll
                for (int kt = 0; kt < 8; kt++) {
                    float4 f0 = *(const float4*)(ep + kt * 32);
                    float4 f1 = *(const float4*)(ep + kt * 32 + 4);
                    union { unsigned short s[8]; short8 v; } u;
                    u.s[0]=f2bf(f0.x); u.s[1]=f2bf(f0.y); u.s[2]=f2bf(f0.z); u.s[3]=f2bf(f0.w);
                    u.s[4]=f2bf(f1.x); u.s[5]=f2bf(f1.y); u.s[6]=f2bf(f1.z); u.s[7]=f2bf(f1.w);
                    #pragma unroll
                    for (int gate = 0; gate < 4; gate++) {
                        short8 bv = *(const short8*)(wlane + (size_t)(gate * KT + kt) * 512);
                        acc[gate] = __builtin_amdgcn_mfma_f32_16x16x32_bf16(u.v, bv, acc[gate], 0, 0, 0);
                    }
                }
            } else {
                const unsigned short* xp = xbf + ((size_t)p * BB + myrow) * EE + q8;
                #pragma unroll
                for (int kt = 0; kt < 8; kt++)
                    xv[kt] = *(const short8*)(xp + kt * 32);
            }
        }

        if (layer == 0) {
            if (p < TT) {
                // ---- single-wave poll: OWN layer only (lanes<32) ----
                if (tid < 64) {
                    for (;;) {
                        bool bad = (lane < 32) && ((int)cldu(pollp) < p);
                        if (__ballot(bad) == 0ULL) break;
                        __builtin_amdgcn_s_sleep(1);
                    }
                }
                __syncthreads();

                const unsigned short* h0r = h0buf + (size_t)(p & 15) * HS;   // h0(p)
                unsigned short* hw = h0buf + (size_t)((p + 1) & 15) * HS;
                const unsigned short* ah = h0r + (size_t)myrow * UU + q8;
                short8 hb[16];
                #pragma unroll
                for (int i = 0; i < 16; i++) hb[i] = cld16c(ah + i * 32);    // kt 8..23
                if (use_xbf) {   // x-MFMAs hide the h load latency (kt order unchanged)
                    #pragma unroll
                    for (int kt = 0; kt < 8; kt++) {
                        #pragma unroll
                        for (int gate = 0; gate < 4; gate++) {
                            short8 bv = *(const short8*)(wlane + (size_t)(gate * KT + kt) * 512);
                            acc[gate] = __builtin_amdgcn_mfma_f32_16x16x32_bf16(xv[kt], bv, acc[gate], 0, 0, 0);
                        }
                    }
                }
                asm volatile("s_waitcnt vmcnt(0)" ::: "memory");
                __builtin_amdgcn_sched_barrier(0);
                #pragma unroll
                for (int i = 0; i < 16; i++) {
                    #pragma unroll
                    for (int gate = 0; gate < 4; gate++) {
                        short8 bv = *(const short8*)(wlane + (size_t)(gate * KT + 8 + i) * 512);
                        acc[gate] = __builtin_amdgcn_mfma_f32_16x16x32_bf16(hb[i], bv, acc[gate], 0, 0, 0);
                    }
                }

                // gating; stage h to LDS (stride 24)
                #pragma unroll
                for (int r = 0; r < 4; r++) {
                    float zi = acc[0][r];
                    float zf = acc[1][r];
                    float zg = acc[2][r];
                    float zo = acc[3][r];
                    float cn = sigf(zf) * cst[r] + sigf(zi) * tanhf(zg);
                    cst[r] = cn;
                    hst[(w * 16 + q * 4 + r) * 24 + n16] = f2bf(sigf(zo) * tanhf(cn));
                }
                __syncthreads();

                // ---- DEFERRED overwrite gate: L1 flags >= p-6 (off the
                // pre-load path; also bounds L0->L1 skew <= 6 < fence period 8
                // for cached-read safety) ----
                {
                    const int thr = p - 6;
                    if (thr > 0) {
                        for (;;) {
                            bool bad = (lane >= 32) && ((int)cldu(pollp) < thr);
                            if (__ballot(bad) == 0ULL) break;
                            __builtin_amdgcn_s_sleep(1);
                        }
                    }
                }
                if (tid < 128) {
                    int row = tid >> 1, half = tid & 1;
                    u64x2 sv = *(const u64x2*)(hst + row * 24 + half * 8);
                    unsigned long long* dp = (unsigned long long*)
                        (hw + (size_t)(row0 + row) * UU + u0 + half * 8);
                    cst16w(dp, sv);
                }
            }
        } else {
            if (p >= 1) {
                const unsigned short* h0r = h0buf + (size_t)(p & 15) * HS;       // h0(p)
                const unsigned short* h1r = h1buf + (size_t)((p - 1) & 15) * HS; // h1(p-1)
                unsigned short* hw = h1buf + (size_t)(p & 15) * HS;
                const unsigned short* a0 = h0r + (size_t)myrow * UU + q8;
                const unsigned short* a1 = h1r + (size_t)myrow * UU + q8;

                // ---- phase A: L0 flags >= p (lanes<32); usually instant ----
                for (;;) {
                    bool bad = (lane < 32) && ((int)cldu(pollp) < p);
                    if (__ballot(bad) == 0ULL) break;
                    __builtin_amdgcn_s_sleep(1);
                }
                short8 ha[16];
                #pragma unroll
                for (int i = 0; i < 16; i++) ha[i] = cld16c(a0 + i * 32);   // kt 0..15

                // ---- phase B: L1 flags >= p (lanes>=32); the binding wait ----
                for (;;) {
                    bool bad = (lane >= 32) && ((int)cldu(pollp) < p);
                    if (__ballot(bad) == 0ULL) break;
                    __builtin_amdgcn_s_sleep(1);
                }
                short8 hc[16];
                #pragma unroll
                for (int i = 0; i < 16; i++) hc[i] = cld16c(a1 + i * 32);   // kt 16..31

                asm volatile("s_waitcnt vmcnt(16)" ::: "memory");   // ha ready (hc in flight)
                __builtin_amdgcn_sched_barrier(0);
                #pragma unroll
                for (int i = 0; i < 16; i++) {
                    #pragma unroll
                    for (int gate = 0; gate < 4; gate++) {
                        short8 bv = *(const short8*)(wlane + (size_t)(gate * KT + i) * 512);
                        acc[gate] = __builtin_amdgcn_mfma_f32_16x16x32_bf16(ha[i], bv, acc[gate], 0, 0, 0);
                    }
                }
                asm volatile("s_waitcnt vmcnt(0)" ::: "memory");    // hc ready
                __builtin_amdgcn_sched_barrier(0);
                #pragma unroll
                for (int i = 0; i < 16; i++) {
                    #pragma unroll
                    for (int gate = 0; gate < 4; gate++) {
                        short8 bv = *(const short8*)(wlane + (size_t)(gate * KT + 16 + i) * 512);
                        acc[gate] = __builtin_amdgcn_mfma_f32_16x16x32_bf16(hc[i], bv, acc[gate], 0, 0, 0);
                    }
                }

                // gating; stage h to LDS (stride 24)
                #pragma unroll
                for (int r = 0; r < 4; r++) {
                    float zi = acc[0][r];
                    float zf = acc[1][r];
                    float zg = acc[2][r];
                    float zo = acc[3][r];
                    float cn = sigf(zf) * cst[r] + sigf(zi) * tanhf(zg);
                    cst[r] = cn;
                    hst[(w * 16 + q * 4 + r) * 24 + n16] = f2bf(sigf(zo) * tanhf(cn));
                }
                __syncthreads();
                if (tid < 128) {
                    int row = tid >> 1, half = tid & 1;
                    u64x2 sv = *(const u64x2*)(hst + row * 24 + half * 8);
                    unsigned long long* dp = (unsigned long long*)
                        (hw + (size_t)(row0 + row) * UU + u0 + half * 8);
                    cst16w(dp, sv);
                }
            }
        }

        // ---- arrive(p): every wave drains its own vmem, then tid0 flags ----
        if (p < TT) {
            asm volatile("s_waitcnt vmcnt(0)" ::: "memory");
            __syncthreads();
            if (tid == 0) cstu(myFlag, (unsigned int)(p + 1));
        }
    }
}

// ---------- final dense: out[b] = sigmoid(h1 . Wd + bd) ----------
__global__ __launch_bounds__(64) void dense_out(
    const unsigned short* __restrict__ h, const float* __restrict__ Wd,
    const float* __restrict__ bd, float* __restrict__ out)
{
    int b = blockIdx.x;
    int lane = threadIdx.x;
    float s = 0.f;
    #pragma unroll
    for (int k = lane; k < UU; k += 64) s += bf2f(h[(size_t)b * UU + k]) * Wd[k];
    #pragma unroll
    for (int off = 32; off > 0; off >>= 1) s += __shfl_down(s, off);
    if (lane == 0) out[b] = sigf(s + bd[0]);
}

extern "C" void kernel_launch(void* const* d_in, const int* in_sizes, int n_in,
                              void* d_out, int out_size, void* d_ws, size_t ws_size,
                              hipStream_t stream) {
    const int*   tokens = (const int*)  d_in[0];
    const float* emb    = (const float*)d_in[1];
    const float* W0     = (const float*)d_in[2];
    const float* U0     = (const float*)d_in[3];
    const float* b0     = (const float*)d_in[4];
    const float* W1     = (const float*)d_in[5];
    const float* U1     = (const float*)d_in[6];
    const float* b1     = (const float*)d_in[7];
    const float* Wd     = (const float*)d_in[8];
    const float* bd     = (const float*)d_in[9];
    float* out = (float*)d_out;

    // ws layout (bytes):
    // [Wt0 3MB][Wt1 4MB][h0 ring x16 4MB][h1 ring x16 4MB][bars 32KB][xbf 32MB]
    const size_t SLOT = (size_t)BB * UU * 2;                  // 262,144
    const size_t oWt0 = 0;
    const size_t oWt1 = (size_t)G4 * 768 * 2;                 // 3,145,728
    const size_t oH0  = oWt1 + (size_t)G4 * 1024 * 2;         // 7,340,032
    const size_t oH1  = oH0 + 16 * SLOT;                      // +4,194,304
    const size_t oBar = oH1 + 16 * SLOT;                      // +4,194,304
    const size_t oX   = oBar + 32768;
    const size_t needFull = oX + (size_t)TT * BB * EE * 2;    // ~47.0 MB
    int use_xbf = (ws_size >= needFull) ? 1 : 0;

    unsigned short* Wt0p = (unsigned short*)((char*)d_ws + oWt0);
    unsigned short* Wt1p = (unsigned short*)((char*)d_ws + oWt1);
    unsigned short* h0p  = (unsigned short*)((char*)d_ws + oH0);
    unsigned short* h1p  = (unsigned short*)((char*)d_ws + oH1);
    unsigned int*   barp = (unsigned int*)  ((char*)d_ws + oBar);
    unsigned short* xbfp = (unsigned short*)((char*)d_ws + oX);

    // only slot 0 of each ring (h(0) = zeros) and the flags need zeroing:
    // every other ring slot is written before it is ever read.
    hipMemsetAsync(h0p, 0, SLOT, stream);
    hipMemsetAsync(h1p, 0, SLOT, stream);
    hipMemsetAsync(barp, 0, 32768, stream);

    wtrans<<<dim3(G4 / 32, EE / 32), dim3(32, 8), 0, stream>>>(W0, EE, Wt0p, 768, 0);
    wtrans<<<dim3(G4 / 32, UU / 32), dim3(32, 8), 0, stream>>>(U0, UU, Wt0p, 768, 256);
    wtrans<<<dim3(G4 / 32, UU / 32), dim3(32, 8), 0, stream>>>(W1, UU, Wt1p, 1024, 0);
    wtrans<<<dim3(G4 / 32, UU / 32), dim3(32, 8), 0, stream>>>(U1, UU, Wt1p, 1024, 512);

    if (use_xbf)
        xgather<<<dim3(BB * TT), dim3(64), 0, stream>>>(tokens, emb, xbfp);

    {
        const size_t shmem = 131072 + 3072 + 256;   // wl + hst + tokl
        hipFuncSetAttribute((const void*)rnn_persist,
                            hipFuncAttributeMaxDynamicSharedMemorySize, (int)shmem);
        void* args[] = {(void*)&Wt0p, (void*)&Wt1p, (void*)&xbfp,
                        (void*)&tokens, (void*)&emb, (void*)&b0, (void*)&b1,
                        (void*)&h0p, (void*)&h1p, (void*)&barp, (void*)&use_xbf};
        hipLaunchCooperativeKernel((const void*)rnn_persist, dim3(256), dim3(256),
                                   args, shmem, stream);
    }

    dense_out<<<dim3(BB), dim3(64), 0, stream>>>(h1p, Wd, bd, out);   // h1(256) = slot 256&15 = 0
}